// Round 6
// baseline (1594.734 us; speedup 1.0000x reference)
//
#include <hip/hip_runtime.h>
#include <math.h>

#define T_ 16
#define N_ 6400
#define E_ 65536
#define IN_ 128
#define ED_ 16
#define H_ 256
#define B_ 64
#define HEADS_ 8
#define L_ 2
#define DFF_ 2048
#define OUT_ 8
#define DH_ 32
#define S_ 17
#define M_TX (B_ * S_)  // 1088

typedef unsigned short u16;
typedef short bf16x8 __attribute__((ext_vector_type(8)));
typedef float f32x4 __attribute__((ext_vector_type(4)));

__device__ __forceinline__ u16 f2bf(float x) {
  unsigned u = __float_as_uint(x);
  unsigned r = (u + 0x7FFFu + ((u >> 16) & 1)) >> 16;
  return (u16)r;
}
__device__ __forceinline__ float bf2f(u16 h) {
  return __uint_as_float(((unsigned)h) << 16);
}

// ---------------- utility ----------------
__global__ void zero_k(float* __restrict__ p, long n) {
  long i = (long)blockIdx.x * 256 + threadIdx.x;
  if (i < n) p[i] = 0.f;
}
__global__ void wzero_k(u16* __restrict__ p, long n) {
  long i = (long)blockIdx.x * 256 + threadIdx.x;
  if (i < n) p[i] = 0;
}

// split x rows [128] -> strided [160] bf16 hi/lo planes
__global__ void splitx_k(const float* __restrict__ in, u16* __restrict__ h,
                         u16* __restrict__ l, long n) {
  long i = (long)blockIdx.x * 256 + threadIdx.x;
  if (i < n) {
    const long row = i >> 7;
    const int c = (int)(i & 127);
    const float v = in[i];
    const u16 hi = f2bf(v);
    h[row * 160 + c] = hi;
    l[row * 160 + c] = f2bf(v - bf2f(hi));
  }
}

// transpose+split W[K][Nc] (fp32) -> Th/Tl[(row_off+n)*ldk + k_off + k]; grid (Nc/16, K/16)
__launch_bounds__(256) __global__
void wtrans_k(const float* __restrict__ W, int Nc, u16* __restrict__ Th,
              u16* __restrict__ Tl, int row_off, int k_off, int ldk) {
  __shared__ float s[16][17];
  const int kt = blockIdx.y * 16, nt = blockIdx.x * 16;
  const int a = threadIdx.x >> 4, b2 = threadIdx.x & 15;
  s[a][b2] = W[(long)(kt + a) * Nc + nt + b2];
  __syncthreads();
  const float v = s[b2][a];  // k = kt+b2, n = nt+a
  const u16 hi = f2bf(v);
  const long o = (long)(row_off + nt + a) * ldk + k_off + kt + b2;
  Th[o] = hi;
  Tl[o] = f2bf(v - bf2f(hi));
}

__global__ void biascat_k(const float* __restrict__ b1, const float* __restrict__ b2,
                          float* __restrict__ o) {
  const int i = threadIdx.x;
  o[i] = (i < 256) ? b1[i] : b2[i - 256];
}

// ---------------- flat MFMA GEMM (no LDS, pre-split bf16 x3) ----------------
// O[M,Nc] = A[M,K(lda)] @ Wt[Nc,K(ldw)]^T. 64x128 tile, 4 waves (wm x wn), wave 32x64.
// Fragments loaded directly from global (A planes [M][lda], W planes [Nc][ldw]).
// EP: 0 none, 1 relu, 3 score-epilogue (atomicAdd tanh(v+bias).scw into sc, no O).
// SPLITK>1: blockIdx.z = k-chunk, atomicAdd into pre-zeroed O, bias chunk0 only.
template <int EP, int SPLITK, int OUTBF>
__launch_bounds__(256) __global__
void gemm_flat(const u16* __restrict__ Ah, const u16* __restrict__ Al, int lda,
               const u16* __restrict__ Wth, const u16* __restrict__ Wtl, int ldw,
               const float* __restrict__ bias,
               float* __restrict__ O, u16* __restrict__ Oh, u16* __restrict__ Ol,
               int ldo, int K, float* __restrict__ sc, const float* __restrict__ scw) {
  const int n0 = blockIdx.x * 128;
  const int m0 = blockIdx.y * 64;
  const int tid = threadIdx.x;
  const int lane = tid & 63;
  const int wave = tid >> 6;
  const int wm = wave & 1;
  const int wn = wave >> 1;
  const int r15 = lane & 15;
  const int q8 = (lane >> 4) << 3;
  const int quad4 = (lane >> 4) << 2;

  int kbeg = 0, kend = K;
  if (SPLITK > 1) {
    const int ch = K / SPLITK;
    kbeg = blockIdx.z * ch;
    kend = kbeg + ch;
  }

  const u16* arh[2];
  const u16* arl[2];
  const u16* brh[4];
  const u16* brl[4];
#pragma unroll
  for (int i = 0; i < 2; ++i) {
    const long o = (long)(m0 + wm * 32 + i * 16 + r15) * lda + q8;
    arh[i] = Ah + o;
    arl[i] = Al + o;
  }
#pragma unroll
  for (int j = 0; j < 4; ++j) {
    const long o = (long)(n0 + wn * 64 + j * 16 + r15) * ldw + q8;
    brh[j] = Wth + o;
    brl[j] = Wtl + o;
  }

  f32x4 acc[2][4];
#pragma unroll
  for (int i = 0; i < 2; ++i)
#pragma unroll
    for (int j = 0; j < 4; ++j) acc[i][j] = (f32x4){0.f, 0.f, 0.f, 0.f};

  for (int k0 = kbeg; k0 < kend; k0 += 32) {
    bf16x8 ah[2], al[2], bh[4], bl[4];
#pragma unroll
    for (int i = 0; i < 2; ++i) {
      ah[i] = *(const bf16x8*)(arh[i] + k0);
      al[i] = *(const bf16x8*)(arl[i] + k0);
    }
#pragma unroll
    for (int j = 0; j < 4; ++j) {
      bh[j] = *(const bf16x8*)(brh[j] + k0);
      bl[j] = *(const bf16x8*)(brl[j] + k0);
    }
#pragma unroll
    for (int i = 0; i < 2; ++i)
#pragma unroll
      for (int j = 0; j < 4; ++j) {
        acc[i][j] = __builtin_amdgcn_mfma_f32_16x16x32_bf16(ah[i], bh[j], acc[i][j], 0, 0, 0);
        acc[i][j] = __builtin_amdgcn_mfma_f32_16x16x32_bf16(ah[i], bl[j], acc[i][j], 0, 0, 0);
        acc[i][j] = __builtin_amdgcn_mfma_f32_16x16x32_bf16(al[i], bh[j], acc[i][j], 0, 0, 0);
      }
  }

  if (EP == 3) {
    // score epilogue: part(row) = sum_cols tanh(v + bias[col]) * scw[col]
#pragma unroll
    for (int i = 0; i < 2; ++i) {
#pragma unroll
      for (int r = 0; r < 4; ++r) {
        float part = 0.f;
#pragma unroll
        for (int j = 0; j < 4; ++j) {
          const int col = n0 + wn * 64 + j * 16 + r15;
          part += tanhf(acc[i][j][r] + bias[col]) * scw[col];
        }
#pragma unroll
        for (int m = 1; m < 16; m <<= 1) part += __shfl_xor(part, m, 64);
        if (r15 == 0)
          atomicAdd(&sc[m0 + wm * 32 + i * 16 + quad4 + r], part);
      }
    }
    return;
  }

#pragma unroll
  for (int i = 0; i < 2; ++i) {
#pragma unroll
    for (int j = 0; j < 4; ++j) {
      const int col = n0 + wn * 64 + j * 16 + r15;
      const int rbase = m0 + wm * 32 + i * 16 + quad4;
      const float bv = bias ? bias[col] : 0.f;
#pragma unroll
      for (int r = 0; r < 4; ++r) {
        float v = acc[i][j][r];
        if (SPLITK == 1) {
          v += bv;
          if (EP == 1) v = fmaxf(v, 0.f);
          if (OUTBF) {
            const u16 hi = f2bf(v);
            Oh[(long)(rbase + r) * ldo + col] = hi;
            Ol[(long)(rbase + r) * ldo + col] = f2bf(v - bf2f(hi));
          } else {
            O[(long)(rbase + r) * ldo + col] = v;
          }
        } else {
          if (blockIdx.z == 0) v += bv;
          atomicAdd(&O[(long)(rbase + r) * ldo + col], v);
        }
      }
    }
  }
}

// ---------------- CSR build ----------------
__global__ void deg_k(const int* __restrict__ eib, int* __restrict__ deg, int t0) {
  const int z = blockIdx.y;
  const int e = blockIdx.x * 256 + threadIdx.x;
  const int dst = eib[(long)(t0 + z) * 2 * E_ + E_ + e];
  atomicAdd(&deg[z * N_ + dst], 1);
}

__launch_bounds__(256) __global__
void scan_k(const int* __restrict__ deg, int* __restrict__ offs, int* __restrict__ cursor) {
  const int z = blockIdx.x, tid = threadIdx.x;
  const int* d = deg + (long)z * N_;
  const int base = tid * 25;
  int loc[25];
  int s = 0;
#pragma unroll
  for (int i = 0; i < 25; ++i) {
    loc[i] = s;
    s += d[base + i];
  }
  __shared__ int ps[256];
  ps[tid] = s;
  __syncthreads();
  for (int off = 1; off < 256; off <<= 1) {
    int v = 0;
    if (tid >= off) v = ps[tid - off];
    __syncthreads();
    if (tid >= off) ps[tid] += v;
    __syncthreads();
  }
  const int pre = (tid == 0) ? 0 : ps[tid - 1];
#pragma unroll
  for (int i = 0; i < 25; ++i) {
    const int o = pre + loc[i];
    offs[(long)z * (N_ + 1) + base + i] = o;
    cursor[(long)z * N_ + base + i] = o;
  }
  if (tid == 255) offs[(long)z * (N_ + 1) + N_] = ps[255];
}

__global__ void fill_k(const int* __restrict__ eib, int* __restrict__ cursor,
                       int* __restrict__ elist, int* __restrict__ srcs, int t0) {
  const int z = blockIdx.y;
  const int e = blockIdx.x * 256 + threadIdx.x;
  const int* base = eib + (long)(t0 + z) * 2 * E_;
  const int src = base[e];
  const int dst = base[E_ + e];
  const int slot = atomicAdd(&cursor[z * N_ + dst], 1);
  elist[(long)z * E_ + slot] = e;
  srcs[(long)z * E_ + slot] = src;
}

__global__ void bounds_k(const int* __restrict__ batchb, int* __restrict__ gb, int t0) {
  const int z = blockIdx.x;
  const int g = threadIdx.x;
  if (g > B_) return;
  const int* bt = batchb + (long)(t0 + z) * N_;
  int lo = 0, hi = N_;
  while (lo < hi) {
    const int mid = (lo + hi) >> 1;
    if (bt[mid] < g) lo = mid + 1; else hi = mid;
  }
  gb[z * (B_ + 1) + g] = lo;
}

// ---------------- per-node mean of edge attrs -> two split K-ext destinations ----------
// 256 thr = 8 nodes x 32 cols (cols >= 16 write zeros)
__launch_bounds__(256) __global__
void eagg_k(const float* __restrict__ eab, const int* __restrict__ elist,
            const int* __restrict__ offs,
            u16* __restrict__ h0, u16* __restrict__ l0,
            u16* __restrict__ h1, u16* __restrict__ l1, int t0) {
  const int z = blockIdx.y;
  const int ln = threadIdx.x >> 5;
  const int c = threadIdx.x & 31;
  const int n = blockIdx.x * 8 + ln;
  float v = 0.f;
  if (c < ED_) {
    const int beg = offs[(long)z * (N_ + 1) + n];
    const int end = offs[(long)z * (N_ + 1) + n + 1];
    const float* ea = eab + (long)(t0 + z) * E_ * ED_;
    const int* el = elist + (long)z * E_;
    for (int j = beg; j < end; ++j) v += ea[(long)el[j] * ED_ + c];
    v /= fmaxf((float)(end - beg), 1.f);
  }
  const u16 hi = f2bf(v);
  const u16 lo = f2bf(v - bf2f(hi));
  const long row = (long)z * N_ + n;
  h0[row * 160 + 128 + c] = hi;
  l0[row * 160 + 128 + c] = lo;
  h1[row * 288 + 256 + c] = hi;
  l1[row * 288 + 256 + c] = lo;
}

// ---------------- fused conv gather: reads F[M][512] (xw|pre), LN, bf16 out ld 288 ----
__launch_bounds__(256) __global__
void conv_gather_k(const float* __restrict__ F, const int* __restrict__ srcs,
                   const int* __restrict__ offs, const float* __restrict__ g,
                   const float* __restrict__ bb, u16* __restrict__ outh,
                   u16* __restrict__ outl) {
  const int z = blockIdx.y;
  const int wid = threadIdx.x >> 6;
  const int lane = threadIdx.x & 63;
  const int n = blockIdx.x * 4 + wid;
  const int beg = offs[(long)z * (N_ + 1) + n];
  const int end = offs[(long)z * (N_ + 1) + n + 1];
  const int* sp = srcs + (long)z * E_;
  const float* Fz = F + (long)z * N_ * 512;
  const int co = lane << 2;
  float4 v = make_float4(0.f, 0.f, 0.f, 0.f);
  int j = beg;
  for (; j + 1 < end; j += 2) {
    const int s0 = sp[j], s1 = sp[j + 1];
    const float4 a = *(const float4*)(Fz + (long)s0 * 512 + co);
    const float4 b2 = *(const float4*)(Fz + (long)s1 * 512 + co);
    v.x += a.x + b2.x;
    v.y += a.y + b2.y;
    v.z += a.z + b2.z;
    v.w += a.w + b2.w;
  }
  if (j < end) {
    const float4 a = *(const float4*)(Fz + (long)sp[j] * 512 + co);
    v.x += a.x;
    v.y += a.y;
    v.z += a.z;
    v.w += a.w;
  }
  const float inv = 1.f / fmaxf((float)(end - beg), 1.f);
  const float4 p = *(const float4*)(Fz + (long)n * 512 + 256 + co);
  const float o0 = fmaxf(fmaf(v.x, inv, p.x), 0.f);
  const float o1 = fmaxf(fmaf(v.y, inv, p.y), 0.f);
  const float o2 = fmaxf(fmaf(v.z, inv, p.z), 0.f);
  const float o3 = fmaxf(fmaf(v.w, inv, p.w), 0.f);
  float s = o0 + o1 + o2 + o3;
  float q = o0 * o0 + o1 * o1 + o2 * o2 + o3 * o3;
#pragma unroll
  for (int m = 1; m < 64; m <<= 1) {
    s += __shfl_xor(s, m, 64);
    q += __shfl_xor(q, m, 64);
  }
  const float mean = s * (1.f / H_);
  const float var = q * (1.f / H_) - mean * mean;
  const float r = rsqrtf(var + 1e-5f);
  const float4 gg = *(const float4*)(g + co);
  const float4 bv = *(const float4*)(bb + co);
  float o[4];
  o[0] = (o0 - mean) * r * gg.x + bv.x;
  o[1] = (o1 - mean) * r * gg.y + bv.y;
  o[2] = (o2 - mean) * r * gg.z + bv.z;
  o[3] = (o3 - mean) * r * gg.w + bv.w;
  const long row = ((long)z * N_ + n) * 288 + co;
  ushort4 hv, lv;
  hv.x = f2bf(o[0]); lv.x = f2bf(o[0] - bf2f(hv.x));
  hv.y = f2bf(o[1]); lv.y = f2bf(o[1] - bf2f(hv.y));
  hv.z = f2bf(o[2]); lv.z = f2bf(o[2] - bf2f(hv.z));
  hv.w = f2bf(o[3]); lv.w = f2bf(o[3] - bf2f(hv.w));
  *(ushort4*)(outh + row) = hv;
  *(ushort4*)(outl + row) = lv;
}

// ---------------- pooling (h planes ld 288) ----------------
__launch_bounds__(256) __global__
void pool_k(const u16* __restrict__ hh, const u16* __restrict__ hl,
            const float* __restrict__ sbuf, const int* __restrict__ gb,
            float* __restrict__ pooled, int t0) {
  const int z = blockIdx.y;
  const int g = blockIdx.x;
  const int c = threadIdx.x;
  const int beg = gb[z * (B_ + 1) + g];
  const int end = gb[z * (B_ + 1) + g + 1];
  const float* sz = sbuf + (long)z * N_;
  __shared__ float red[256];
  float m = -1e30f;
  for (int i = beg + c; i < end; i += 256) m = fmaxf(m, sz[i]);
  red[c] = m;
  __syncthreads();
  for (int s = 128; s > 0; s >>= 1) {
    if (c < s) red[c] = fmaxf(red[c], red[c + s]);
    __syncthreads();
  }
  m = red[0];
  __syncthreads();
  float sum = 0.f;
  for (int i = beg + c; i < end; i += 256) sum += expf(sz[i] - m);
  red[c] = sum;
  __syncthreads();
  for (int s = 128; s > 0; s >>= 1) {
    if (c < s) red[c] += red[c + s];
    __syncthreads();
  }
  sum = red[0];
  float acc = 0.f;
  for (int i = beg; i < end; ++i) {
    const float w = expf(sz[i] - m);
    const long idx = ((long)z * N_ + i) * 288 + c;
    acc = fmaf(bf2f(hh[idx]) + bf2f(hl[idx]), w, acc);
  }
  pooled[((long)(t0 + z) * B_ + g) * H_ + c] = (sum > 0.f) ? acc / sum : 0.f;
}

// ---------------- transformer ----------------
__global__ void build_seq_k(const float* __restrict__ pooled, const float* __restrict__ cls,
                            const float* __restrict__ pos, float* __restrict__ seq,
                            u16* __restrict__ sh, u16* __restrict__ sl) {
  const int s = blockIdx.x, b = blockIdx.y, c = threadIdx.x;
  const float v0 = (s == 0) ? cls[c] : pooled[(((long)(s - 1)) * B_ + b) * H_ + c];
  const float v = v0 + pos[(long)s * H_ + c];
  const long o = ((long)b * S_ + s) * H_ + c;
  seq[o] = v;
  const u16 hi = f2bf(v);
  sh[o] = hi;
  sl[o] = f2bf(v - bf2f(hi));
}

__launch_bounds__(256) __global__
void attn_k(const float* __restrict__ qkv, u16* __restrict__ oh, u16* __restrict__ ol) {
  const int b = blockIdx.x, h = blockIdx.y;
  __shared__ float qs[S_][DH_], ks[S_][DH_], vs[S_][DH_], att[S_][S_];
  const int tid = threadIdx.x;
  for (int i = tid; i < S_ * DH_; i += 256) {
    const int s = i / DH_, d = i % DH_;
    const long base = ((long)b * S_ + s) * (3 * H_) + h * DH_ + d;
    qs[s][d] = qkv[base];
    ks[s][d] = qkv[base + H_];
    vs[s][d] = qkv[base + 2 * H_];
  }
  __syncthreads();
  for (int i = tid; i < S_ * S_; i += 256) {
    const int r = i / S_, c2 = i % S_;
    float acc = 0.f;
#pragma unroll
    for (int d = 0; d < DH_; ++d) acc = fmaf(qs[r][d], ks[c2][d], acc);
    att[r][c2] = acc * 0.17677669529663687f;
  }
  __syncthreads();
  if (tid < S_) {
    float m = -1e30f;
    for (int j = 0; j < S_; ++j) m = fmaxf(m, att[tid][j]);
    float sum = 0.f;
    for (int j = 0; j < S_; ++j) {
      const float e = expf(att[tid][j] - m);
      att[tid][j] = e;
      sum += e;
    }
    const float inv = 1.f / sum;
    for (int j = 0; j < S_; ++j) att[tid][j] *= inv;
  }
  __syncthreads();
  for (int i = tid; i < S_ * DH_; i += 256) {
    const int s = i / DH_, d = i % DH_;
    float acc = 0.f;
#pragma unroll
    for (int j = 0; j < S_; ++j) acc = fmaf(att[s][j], vs[j][d], acc);
    const long o = ((long)b * S_ + s) * H_ + h * DH_ + d;
    const u16 hi = f2bf(acc);
    oh[o] = hi;
    ol[o] = f2bf(acc - bf2f(hi));
  }
}

__launch_bounds__(256) __global__
void resid_ln_k(float* __restrict__ seq, const float* __restrict__ add,
                const float* __restrict__ g, const float* __restrict__ bb,
                u16* __restrict__ sh, u16* __restrict__ sl) {
  const int row = blockIdx.x, c = threadIdx.x;
  const float v = seq[(long)row * H_ + c] + add[(long)row * H_ + c];
  __shared__ float rs[256], rq[256];
  rs[c] = v;
  rq[c] = v * v;
  __syncthreads();
  for (int s = 128; s > 0; s >>= 1) {
    if (c < s) {
      rs[c] += rs[c + s];
      rq[c] += rq[c + s];
    }
    __syncthreads();
  }
  const float mean = rs[0] * (1.f / H_);
  const float var = rq[0] * (1.f / H_) - mean * mean;
  const float o = (v - mean) * rsqrtf(var + 1e-5f) * g[c] + bb[c];
  const long idx = (long)row * H_ + c;
  seq[idx] = o;
  const u16 hi = f2bf(o);
  sh[idx] = hi;
  sl[idx] = f2bf(o - bf2f(hi));
}

__launch_bounds__(256) __global__
void head_k(const float* __restrict__ seq, const float* __restrict__ hw,
            const float* __restrict__ hb, float* __restrict__ out) {
  const int b = blockIdx.x, c = threadIdx.x;
  const float x = seq[(long)b * S_ * H_ + c];
  __shared__ float rs[256];
  for (int o = 0; o < OUT_; ++o) {
    rs[c] = x * hw[c * OUT_ + o];
    __syncthreads();
    for (int s = 128; s > 0; s >>= 1) {
      if (c < s) rs[c] += rs[c + s];
      __syncthreads();
    }
    if (c == 0) {
      const float v = rs[0] + hb[o];
      out[b * OUT_ + o] = fmaxf(v, 0.f) + log1pf(expf(-fabsf(v)));
    }
    __syncthreads();
  }
}

// ---------------- launcher ----------------
extern "C" void kernel_launch(void* const* d_in, const int* in_sizes, int n_in,
                              void* d_out, int out_size, void* d_ws, size_t ws_size,
                              hipStream_t stream) {
  const float* x = (const float*)d_in[0];
  const float* ea = (const float*)d_in[1];
  const int* ei = (const int*)d_in[2];
  const int* batch = (const int*)d_in[3];
  const float* nw0 = (const float*)d_in[4];
  const float* nb0 = (const float*)d_in[5];
  const float* rw0 = (const float*)d_in[6];
  const float* rb0 = (const float*)d_in[7];
  const float* lg0 = (const float*)d_in[8];
  const float* lb0 = (const float*)d_in[9];
  const float* nw1 = (const float*)d_in[10];
  const float* nb1 = (const float*)d_in[11];
  const float* rw1 = (const float*)d_in[12];
  const float* rb1 = (const float*)d_in[13];
  const float* lg1 = (const float*)d_in[14];
  const float* lb1 = (const float*)d_in[15];
  const float* ppw = (const float*)d_in[16];
  const float* ppb = (const float*)d_in[17];
  const float* psw = (const float*)d_in[18];
  // d_in[19] = psb: dropped (softmax shift-invariant)
  const float* pos = (const float*)d_in[20];
  const float* cls = (const float*)d_in[21];
  const float* qkvw = (const float*)d_in[22];
  const float* qkvbias = (const float*)d_in[23];
  const float* outw = (const float*)d_in[24];
  const float* outb = (const float*)d_in[25];
  const float* f1w = (const float*)d_in[26];
  const float* f1b = (const float*)d_in[27];
  const float* f2w = (const float*)d_in[28];
  const float* f2b = (const float*)d_in[29];
  const float* l1g = (const float*)d_in[30];
  const float* l1b = (const float*)d_in[31];
  const float* l2g = (const float*)d_in[32];
  const float* l2b = (const float*)d_in[33];
  const float* hw = (const float*)d_in[34];
  const float* hb = (const float*)d_in[35];
  float* out = (float*)d_out;

  // ---- workspace carve ----
  char* cur = (char*)d_ws;
  auto alloc = [&](long bytes) {
    char* p = cur;
    cur += (bytes + 255) & ~255L;
    return (void*)p;
  };
  float* pooled = (float*)alloc((long)T_ * B_ * H_ * 4);
  float* seq = (float*)alloc((long)M_TX * H_ * 4);
  u16* seqh = (u16*)alloc((long)M_TX * H_ * 2);
  u16* seql = (u16*)alloc((long)M_TX * H_ * 2);
  float* qkvbuf = (float*)alloc((long)M_TX * 3 * H_ * 4);
  float* obuf_f = (float*)alloc((long)M_TX * H_ * 4);
  u16* obufh = (u16*)alloc((long)M_TX * H_ * 2);
  u16* obufl = (u16*)alloc((long)M_TX * H_ * 2);
  u16* ffh = (u16*)alloc((long)M_TX * DFF_ * 2);
  u16* ffl = (u16*)alloc((long)M_TX * DFF_ * 2);
  u16* w0h = (u16*)alloc(512L * 160 * 2);
  u16* w0l = (u16*)alloc(512L * 160 * 2);
  u16* w1h = (u16*)alloc(512L * 288 * 2);
  u16* w1l = (u16*)alloc(512L * 288 * 2);
  u16* ppwh = (u16*)alloc(256L * 256 * 2);
  u16* ppwl = (u16*)alloc(256L * 256 * 2);
  u16* qkvwh = (u16*)alloc((long)L_ * 768 * 256 * 2);
  u16* qkvwl = (u16*)alloc((long)L_ * 768 * 256 * 2);
  u16* outwh = (u16*)alloc((long)L_ * 256 * 256 * 2);
  u16* outwl = (u16*)alloc((long)L_ * 256 * 256 * 2);
  u16* f1wh = (u16*)alloc((long)L_ * 2048 * 256 * 2);
  u16* f1wl = (u16*)alloc((long)L_ * 2048 * 256 * 2);
  u16* f2wh = (u16*)alloc((long)L_ * 256 * 2048 * 2);
  u16* f2wl = (u16*)alloc((long)L_ * 256 * 2048 * 2);
  float* bias0c = (float*)alloc(512 * 4);
  float* bias1c = (float*)alloc(512 * 4);
  const long fixed_used = cur - (char*)d_ws;

  const long perday = (long)N_ * 160 * 2 * 2      // xh/xl (K-ext)
                      + (long)N_ * 512 * 4        // bufF
                      + (long)N_ * 288 * 2 * 2    // bufD planes (K-ext)
                      + (long)N_ * 4              // sbuf
                      + (2L * E_ + 3L * N_ + (N_ + 1) + (B_ + 1)) * 4 + 8192;
  int DT = 16;
  while (DT > 1 && (size_t)(fixed_used + (long)DT * perday) > ws_size) DT >>= 1;

  u16* xh = (u16*)alloc((long)DT * N_ * 160 * 2);
  u16* xl = (u16*)alloc((long)DT * N_ * 160 * 2);
  float* bufF = (float*)alloc((long)DT * N_ * 512 * 4);
  u16* bufDh = (u16*)alloc((long)DT * N_ * 288 * 2);
  u16* bufDl = (u16*)alloc((long)DT * N_ * 288 * 2);
  float* sbuf = (float*)alloc((long)DT * N_ * 4);
  int* elist = (int*)alloc((long)DT * E_ * 4);
  int* srcs = (int*)alloc((long)DT * E_ * 4);
  int* offs = (int*)alloc((long)DT * (N_ + 1) * 4);
  int* cursor = (int*)alloc((long)DT * N_ * 4);
  int* deg = (int*)alloc((long)DT * N_ * 4);
  int* gb = (int*)alloc((long)DT * (B_ + 1) * 4);

  auto zero = [&](float* p, long n) {
    zero_k<<<dim3((unsigned)((n + 255) / 256)), 256, 0, stream>>>(p, n);
  };

  // ---- weight prep (once per launch) ----
  wzero_k<<<dim3((unsigned)((512L * 160 + 255) / 256)), 256, 0, stream>>>(w0h, 512L * 160);
  wzero_k<<<dim3((unsigned)((512L * 160 + 255) / 256)), 256, 0, stream>>>(w0l, 512L * 160);
  wzero_k<<<dim3((unsigned)((512L * 288 + 255) / 256)), 256, 0, stream>>>(w1h, 512L * 288);
  wzero_k<<<dim3((unsigned)((512L * 288 + 255) / 256)), 256, 0, stream>>>(w1l, 512L * 288);
  // layer0: neigh-top (K=128) -> rows 0..255; root (K=128) -> rows 256..511;
  //         Wb0 (K=16) -> rows 256..511 at k_off 128 (eagg goes to root/pre half)
  wtrans_k<<<dim3(16, 8), 256, 0, stream>>>(nw0, 256, w0h, w0l, 0, 0, 160);
  wtrans_k<<<dim3(16, 8), 256, 0, stream>>>(rw0, 256, w0h, w0l, 256, 0, 160);
  wtrans_k<<<dim3(16, 1), 256, 0, stream>>>(nw0 + 128L * 256, 256, w0h, w0l, 256, 128, 160);
  // layer1
  wtrans_k<<<dim3(16, 16), 256, 0, stream>>>(nw1, 256, w1h, w1l, 0, 0, 288);
  wtrans_k<<<dim3(16, 16), 256, 0, stream>>>(rw1, 256, w1h, w1l, 256, 0, 288);
  wtrans_k<<<dim3(16, 1), 256, 0, stream>>>(nw1 + 256L * 256, 256, w1h, w1l, 256, 256, 288);
  wtrans_k<<<dim3(16, 16), 256, 0, stream>>>(ppw, 256, ppwh, ppwl, 0, 0, 256);
  for (int l = 0; l < L_; ++l) {
    wtrans_k<<<dim3(48, 16), 256, 0, stream>>>(qkvw + (long)l * 256 * 768, 768,
                                               qkvwh + (long)l * 768 * 256,
                                               qkvwl + (long)l * 768 * 256, 0, 0, 256);
    wtrans_k<<<dim3(16, 16), 256, 0, stream>>>(outw + (long)l * 256 * 256, 256,
                                               outwh + (long)l * 256 * 256,
                                               outwl + (long)l * 256 * 256, 0, 0, 256);
    wtrans_k<<<dim3(128, 16), 256, 0, stream>>>(f1w + (long)l * 256 * 2048, 2048,
                                                f1wh + (long)l * 2048 * 256,
                                                f1wl + (long)l * 2048 * 256, 0, 0, 256);
    wtrans_k<<<dim3(16, 128), 256, 0, stream>>>(f2w + (long)l * 2048 * 256, 256,
                                                f2wh + (long)l * 256 * 2048,
                                                f2wl + (long)l * 256 * 2048, 0, 0, 2048);
  }
  biascat_k<<<1, 512, 0, stream>>>(nb0, rb0, bias0c);
  biascat_k<<<1, 512, 0, stream>>>(nb1, rb1, bias1c);

  for (int t0 = 0; t0 < T_; t0 += DT) {
    const int zc = DT;
    // ----- CSR + bounds + x split + eagg K-ext fill -----
    zero((float*)deg, (long)zc * N_);
    deg_k<<<dim3(E_ / 256, zc), 256, 0, stream>>>(ei, deg, t0);
    scan_k<<<dim3(zc), 256, 0, stream>>>(deg, offs, cursor);
    fill_k<<<dim3(E_ / 256, zc), 256, 0, stream>>>(ei, cursor, elist, srcs, t0);
    bounds_k<<<dim3(zc), 128, 0, stream>>>(batch, gb, t0);
    {
      const long nx = (long)zc * N_ * 128;
      splitx_k<<<dim3((unsigned)(nx / 256)), 256, 0, stream>>>(x + (long)t0 * N_ * IN_,
                                                               xh, xl, nx);
    }
    eagg_k<<<dim3(N_ / 8, zc), 256, 0, stream>>>(ea, elist, offs, xh, xl, bufDh, bufDl, t0);
    // ----- conv layer 0: fused [neigh|root+eagg] flat GEMM, M = zc*N -----
    gemm_flat<0, 1, 0><<<dim3(4, zc * (N_ / 64)), 256, 0, stream>>>(
        xh, xl, 160, w0h, w0l, 160, bias0c, bufF, nullptr, nullptr, 512, 160,
        nullptr, nullptr);
    conv_gather_k<<<dim3(N_ / 4, zc), 256, 0, stream>>>(bufF, srcs, offs, lg0, lb0,
                                                        bufDh, bufDl);
    // ----- conv layer 1 -----
    gemm_flat<0, 1, 0><<<dim3(4, zc * (N_ / 64)), 256, 0, stream>>>(
        bufDh, bufDl, 288, w1h, w1l, 288, bias1c, bufF, nullptr, nullptr, 512, 288,
        nullptr, nullptr);
    conv_gather_k<<<dim3(N_ / 4, zc), 256, 0, stream>>>(bufF, srcs, offs, lg1, lb1,
                                                        bufDh, bufDl);
    // ----- pooling: fused proj+tanh+score epilogue, then segment softmax -----
    zero(sbuf, (long)zc * N_);
    gemm_flat<3, 1, 0><<<dim3(2, zc * (N_ / 64)), 256, 0, stream>>>(
        bufDh, bufDl, 288, ppwh, ppwl, 256, ppb, nullptr, nullptr, nullptr, 0, 256,
        sbuf, psw);
    pool_k<<<dim3(B_, zc), 256, 0, stream>>>(bufDh, bufDl, sbuf, gb, pooled, t0);
  }

  // ----- temporal transformer -----
  build_seq_k<<<dim3(S_, B_), 256, 0, stream>>>(pooled, cls, pos, seq, seqh, seql);
  for (int l = 0; l < L_; ++l) {
    gemm_flat<0, 1, 0><<<dim3(6, M_TX / 64), 256, 0, stream>>>(
        seqh, seql, 256, qkvwh + (long)l * 768 * 256, qkvwl + (long)l * 768 * 256, 256,
        qkvbias + (long)l * 768, qkvbuf, nullptr, nullptr, 768, 256, nullptr, nullptr);
    attn_k<<<dim3(B_, HEADS_), 256, 0, stream>>>(qkvbuf, obufh, obufl);
    gemm_flat<0, 1, 0><<<dim3(2, M_TX / 64), 256, 0, stream>>>(
        obufh, obufl, 256, outwh + (long)l * 256 * 256, outwl + (long)l * 256 * 256, 256,
        outb + (long)l * H_, obuf_f, nullptr, nullptr, 256, 256, nullptr, nullptr);
    resid_ln_k<<<dim3(M_TX), 256, 0, stream>>>(seq, obuf_f, l1g + (long)l * H_,
                                               l1b + (long)l * H_, seqh, seql);
    gemm_flat<1, 1, 1><<<dim3(16, M_TX / 64), 256, 0, stream>>>(
        seqh, seql, 256, f1wh + (long)l * 2048 * 256, f1wl + (long)l * 2048 * 256, 256,
        f1b + (long)l * DFF_, nullptr, ffh, ffl, 2048, 256, nullptr, nullptr);
    zero(obuf_f, (long)M_TX * H_);
    gemm_flat<0, 8, 0><<<dim3(2, M_TX / 64, 8), 256, 0, stream>>>(
        ffh, ffl, 2048, f2wh + (long)l * 256 * 2048, f2wl + (long)l * 256 * 2048, 2048,
        f2b + (long)l * H_, obuf_f, nullptr, nullptr, 256, 2048, nullptr, nullptr);
    resid_ln_k<<<dim3(M_TX), 256, 0, stream>>>(seq, obuf_f, l2g + (long)l * H_,
                                               l2b + (long)l * H_, seqh, seql);
  }
  head_k<<<dim3(B_), 256, 0, stream>>>(seq, hw, hb, out);
}

// Round 7
// 1214.303 us; speedup vs baseline: 1.3133x; 1.3133x over previous
//
#include <hip/hip_runtime.h>
#include <math.h>

#define T_ 16
#define N_ 6400
#define E_ 65536
#define IN_ 128
#define ED_ 16
#define H_ 256
#define B_ 64
#define HEADS_ 8
#define L_ 2
#define DFF_ 2048
#define OUT_ 8
#define DH_ 32
#define S_ 17
#define M_TX (B_ * S_)  // 1088

typedef unsigned short u16;
typedef short bf16x8 __attribute__((ext_vector_type(8)));
typedef float f32x4 __attribute__((ext_vector_type(4)));

__device__ __forceinline__ u16 f2bf(float x) {
  unsigned u = __float_as_uint(x);
  unsigned r = (u + 0x7FFFu + ((u >> 16) & 1)) >> 16;
  return (u16)r;
}
__device__ __forceinline__ float bf2f(u16 h) {
  return __uint_as_float(((unsigned)h) << 16);
}

// ---------------- utility ----------------
__global__ void zero_k(float* __restrict__ p, long n) {
  long i = (long)blockIdx.x * 256 + threadIdx.x;
  if (i < n) p[i] = 0.f;
}
__global__ void wzero_k(u16* __restrict__ p, long n) {
  long i = (long)blockIdx.x * 256 + threadIdx.x;
  if (i < n) p[i] = 0;
}

// split x rows [128] -> strided [160] bf16 hi/lo planes
__global__ void splitx_k(const float* __restrict__ in, u16* __restrict__ h,
                         u16* __restrict__ l, long n) {
  long i = (long)blockIdx.x * 256 + threadIdx.x;
  if (i < n) {
    const long row = i >> 7;
    const int c = (int)(i & 127);
    const float v = in[i];
    const u16 hi = f2bf(v);
    h[row * 160 + c] = hi;
    l[row * 160 + c] = f2bf(v - bf2f(hi));
  }
}

// transpose+split W[K][Nc] (fp32) -> Th/Tl[(row_off+n)*ldk + k_off + k]; grid (Nc/16, K/16)
__launch_bounds__(256) __global__
void wtrans_k(const float* __restrict__ W, int Nc, u16* __restrict__ Th,
              u16* __restrict__ Tl, int row_off, int k_off, int ldk) {
  __shared__ float s[16][17];
  const int kt = blockIdx.y * 16, nt = blockIdx.x * 16;
  const int a = threadIdx.x >> 4, b2 = threadIdx.x & 15;
  s[a][b2] = W[(long)(kt + a) * Nc + nt + b2];
  __syncthreads();
  const float v = s[b2][a];  // k = kt+b2, n = nt+a
  const u16 hi = f2bf(v);
  const long o = (long)(row_off + nt + a) * ldk + k_off + kt + b2;
  Th[o] = hi;
  Tl[o] = f2bf(v - bf2f(hi));
}

__global__ void biascat_k(const float* __restrict__ b1, const float* __restrict__ b2,
                          float* __restrict__ o) {
  const int i = threadIdx.x;
  o[i] = (i < 256) ? b1[i] : b2[i - 256];
}

// ---------------- LDS MFMA GEMM (pre-split bf16 x3): O[M,Nc] = A@Wt^T ----------------
// A planes [M][lda] row-major; W planes pre-transposed [Nc][ldw].
// 64x128 tile, 4 waves (2 wm x 2 wn), wave = 32x64, 2x4 16x16x32 frags.
// Staging: row=tid>>1, 32 B/lane into pad-40 rows (bank-conflict-free both ways).
// EP: 0 none, 1 relu, 3 score-epilogue (atomicAdd sum tanh(v+bias)*scw into sc).
// OUTM: 0 fp32, 1 split bf16 hi/lo, 2 single bf16.
// SPLITK>1: blockIdx.z = k-chunk, atomicAdd into pre-zeroed fp32 O, bias chunk0 only.
template <int EP, int SPLITK, int OUTM>
__launch_bounds__(256) __global__
void gemm_bf(const u16* __restrict__ Ah, const u16* __restrict__ Al, int lda,
             const u16* __restrict__ Wth, const u16* __restrict__ Wtl, int ldw,
             const float* __restrict__ bias,
             float* __restrict__ O, u16* __restrict__ Oh, u16* __restrict__ Ol,
             int ldo, int K, float* __restrict__ sc, const float* __restrict__ scw) {
  const int n0 = blockIdx.x * 128;
  const int m0 = blockIdx.y * 64;
  const int tid = threadIdx.x;
  const int lane = tid & 63;
  const int wave = tid >> 6;
  const int wm = wave & 1;
  const int wn = wave >> 1;
  const int r15 = lane & 15;
  const int q8 = (lane >> 4) << 3;
  const int quad4 = (lane >> 4) << 2;

  int kbeg = 0, kend = K;
  if (SPLITK > 1) {
    const int ch = K / SPLITK;
    kbeg = blockIdx.z * ch;
    kend = kbeg + ch;
  }

  __shared__ u16 As_h[64 * 40], As_l[64 * 40];
  __shared__ u16 Bs_h[128 * 40], Bs_l[128 * 40];

  f32x4 acc[2][4];
#pragma unroll
  for (int i = 0; i < 2; ++i)
#pragma unroll
    for (int j = 0; j < 4; ++j) acc[i][j] = (f32x4){0.f, 0.f, 0.f, 0.f};

  const int sr = tid >> 1;          // 0..127
  const int sk = (tid & 1) << 4;    // 0 or 16 ushorts
  const u16* agh = Ah + (long)(m0 + (sr & 63)) * lda + sk;
  const u16* agl = Al + (long)(m0 + (sr & 63)) * lda + sk;
  const u16* bgh = Wth + (long)(n0 + sr) * ldw + sk;
  const u16* bgl = Wtl + (long)(n0 + sr) * ldw + sk;
  const int sbase = sr * 40 + sk;

  for (int k0 = kbeg; k0 < kend; k0 += 32) {
    bf16x8 b0h = *(const bf16x8*)(bgh + k0);
    bf16x8 b1h = *(const bf16x8*)(bgh + k0 + 8);
    bf16x8 b0l = *(const bf16x8*)(bgl + k0);
    bf16x8 b1l = *(const bf16x8*)(bgl + k0 + 8);
    bf16x8 a0h, a1h, a0l, a1l;
    if (tid < 128) {
      a0h = *(const bf16x8*)(agh + k0);
      a1h = *(const bf16x8*)(agh + k0 + 8);
      a0l = *(const bf16x8*)(agl + k0);
      a1l = *(const bf16x8*)(agl + k0 + 8);
    }
    __syncthreads();
    *(bf16x8*)&Bs_h[sbase] = b0h;
    *(bf16x8*)&Bs_h[sbase + 8] = b1h;
    *(bf16x8*)&Bs_l[sbase] = b0l;
    *(bf16x8*)&Bs_l[sbase + 8] = b1l;
    if (tid < 128) {
      *(bf16x8*)&As_h[sbase] = a0h;
      *(bf16x8*)&As_h[sbase + 8] = a1h;
      *(bf16x8*)&As_l[sbase] = a0l;
      *(bf16x8*)&As_l[sbase + 8] = a1l;
    }
    __syncthreads();
    bf16x8 ah[2], al[2], bh[4], bl[4];
#pragma unroll
    for (int i = 0; i < 2; ++i) {
      const int ao = (wm * 32 + i * 16 + r15) * 40 + q8;
      ah[i] = *(const bf16x8*)&As_h[ao];
      al[i] = *(const bf16x8*)&As_l[ao];
    }
#pragma unroll
    for (int j = 0; j < 4; ++j) {
      const int bo = (wn * 64 + j * 16 + r15) * 40 + q8;
      bh[j] = *(const bf16x8*)&Bs_h[bo];
      bl[j] = *(const bf16x8*)&Bs_l[bo];
    }
#pragma unroll
    for (int i = 0; i < 2; ++i)
#pragma unroll
      for (int j = 0; j < 4; ++j) {
        acc[i][j] = __builtin_amdgcn_mfma_f32_16x16x32_bf16(ah[i], bh[j], acc[i][j], 0, 0, 0);
        acc[i][j] = __builtin_amdgcn_mfma_f32_16x16x32_bf16(ah[i], bl[j], acc[i][j], 0, 0, 0);
        acc[i][j] = __builtin_amdgcn_mfma_f32_16x16x32_bf16(al[i], bh[j], acc[i][j], 0, 0, 0);
      }
  }

  if (EP == 3) {
    // score epilogue: row-sum of tanh(v + bias[col]) * scw[col]
#pragma unroll
    for (int i = 0; i < 2; ++i) {
#pragma unroll
      for (int r = 0; r < 4; ++r) {
        float part = 0.f;
#pragma unroll
        for (int j = 0; j < 4; ++j) {
          const int col = n0 + wn * 64 + j * 16 + r15;
          part += tanhf(acc[i][j][r] + bias[col]) * scw[col];
        }
#pragma unroll
        for (int m = 1; m < 16; m <<= 1) part += __shfl_xor(part, m, 64);
        if (r15 == 0)
          atomicAdd(&sc[m0 + wm * 32 + i * 16 + quad4 + r], part);
      }
    }
    return;
  }

#pragma unroll
  for (int i = 0; i < 2; ++i) {
#pragma unroll
    for (int j = 0; j < 4; ++j) {
      const int col = n0 + wn * 64 + j * 16 + r15;
      const int rbase = m0 + wm * 32 + i * 16 + quad4;
      const float bv = bias ? bias[col] : 0.f;
#pragma unroll
      for (int r = 0; r < 4; ++r) {
        float v = acc[i][j][r];
        if (SPLITK == 1) {
          v += bv;
          if (EP == 1) v = fmaxf(v, 0.f);
          if (OUTM == 0) {
            O[(long)(rbase + r) * ldo + col] = v;
          } else if (OUTM == 1) {
            const u16 hi = f2bf(v);
            Oh[(long)(rbase + r) * ldo + col] = hi;
            Ol[(long)(rbase + r) * ldo + col] = f2bf(v - bf2f(hi));
          } else {
            Oh[(long)(rbase + r) * ldo + col] = f2bf(v);
          }
        } else {
          if (blockIdx.z == 0) v += bv;
          atomicAdd(&O[(long)(rbase + r) * ldo + col], v);
        }
      }
    }
  }
}

// ---------------- CSR build ----------------
__global__ void deg_k(const int* __restrict__ eib, int* __restrict__ deg, int t0) {
  const int z = blockIdx.y;
  const int e = blockIdx.x * 256 + threadIdx.x;
  const int dst = eib[(long)(t0 + z) * 2 * E_ + E_ + e];
  atomicAdd(&deg[z * N_ + dst], 1);
}

__launch_bounds__(256) __global__
void scan_k(const int* __restrict__ deg, int* __restrict__ offs, int* __restrict__ cursor) {
  const int z = blockIdx.x, tid = threadIdx.x;
  const int* d = deg + (long)z * N_;
  const int base = tid * 25;
  int loc[25];
  int s = 0;
#pragma unroll
  for (int i = 0; i < 25; ++i) {
    loc[i] = s;
    s += d[base + i];
  }
  __shared__ int ps[256];
  ps[tid] = s;
  __syncthreads();
  for (int off = 1; off < 256; off <<= 1) {
    int v = 0;
    if (tid >= off) v = ps[tid - off];
    __syncthreads();
    if (tid >= off) ps[tid] += v;
    __syncthreads();
  }
  const int pre = (tid == 0) ? 0 : ps[tid - 1];
#pragma unroll
  for (int i = 0; i < 25; ++i) {
    const int o = pre + loc[i];
    offs[(long)z * (N_ + 1) + base + i] = o;
    cursor[(long)z * N_ + base + i] = o;
  }
  if (tid == 255) offs[(long)z * (N_ + 1) + N_] = ps[255];
}

__global__ void fill_k(const int* __restrict__ eib, int* __restrict__ cursor,
                       int* __restrict__ elist, int* __restrict__ srcs, int t0) {
  const int z = blockIdx.y;
  const int e = blockIdx.x * 256 + threadIdx.x;
  const int* base = eib + (long)(t0 + z) * 2 * E_;
  const int src = base[e];
  const int dst = base[E_ + e];
  const int slot = atomicAdd(&cursor[z * N_ + dst], 1);
  elist[(long)z * E_ + slot] = e;
  srcs[(long)z * E_ + slot] = src;
}

__global__ void bounds_k(const int* __restrict__ batchb, int* __restrict__ gb, int t0) {
  const int z = blockIdx.x;
  const int g = threadIdx.x;
  if (g > B_) return;
  const int* bt = batchb + (long)(t0 + z) * N_;
  int lo = 0, hi = N_;
  while (lo < hi) {
    const int mid = (lo + hi) >> 1;
    if (bt[mid] < g) lo = mid + 1; else hi = mid;
  }
  gb[z * (B_ + 1) + g] = lo;
}

// ---------------- per-node mean of edge attrs -> K-ext fills ----------------
// 256 thr = 8 nodes x 32 cols (cols >= 16 write zeros)
__launch_bounds__(256) __global__
void eagg_k(const float* __restrict__ eab, const int* __restrict__ elist,
            const int* __restrict__ offs,
            u16* __restrict__ h0, u16* __restrict__ l0,
            u16* __restrict__ h1, u16* __restrict__ l1, int t0) {
  const int z = blockIdx.y;
  const int ln = threadIdx.x >> 5;
  const int c = threadIdx.x & 31;
  const int n = blockIdx.x * 8 + ln;
  float v = 0.f;
  if (c < ED_) {
    const int beg = offs[(long)z * (N_ + 1) + n];
    const int end = offs[(long)z * (N_ + 1) + n + 1];
    const float* ea = eab + (long)(t0 + z) * E_ * ED_;
    const int* el = elist + (long)z * E_;
    for (int j = beg; j < end; ++j) v += ea[(long)el[j] * ED_ + c];
    v /= fmaxf((float)(end - beg), 1.f);
  }
  const u16 hi = f2bf(v);
  const u16 lo = f2bf(v - bf2f(hi));
  const long row = (long)z * N_ + n;
  h0[row * 160 + 128 + c] = hi;
  l0[row * 160 + 128 + c] = lo;
  h1[row * 288 + 256 + c] = hi;
  l1[row * 288 + 256 + c] = lo;
}

// ---------------- fused conv gather: reads bf16 F[M][512] (xw|pre), LN, split out ----
__launch_bounds__(256) __global__
void conv_gather_k(const u16* __restrict__ F, const int* __restrict__ srcs,
                   const int* __restrict__ offs, const float* __restrict__ g,
                   const float* __restrict__ bb, u16* __restrict__ outh,
                   u16* __restrict__ outl) {
  const int z = blockIdx.y;
  const int wid = threadIdx.x >> 6;
  const int lane = threadIdx.x & 63;
  const int n = blockIdx.x * 4 + wid;
  const int beg = offs[(long)z * (N_ + 1) + n];
  const int end = offs[(long)z * (N_ + 1) + n + 1];
  const int* sp = srcs + (long)z * E_;
  const u16* Fz = F + (long)z * N_ * 512;
  const int co = lane << 2;
  float4 v = make_float4(0.f, 0.f, 0.f, 0.f);
  int j = beg;
  for (; j + 1 < end; j += 2) {
    const int s0 = sp[j], s1 = sp[j + 1];
    const ushort4 a = *(const ushort4*)(Fz + (long)s0 * 512 + co);
    const ushort4 b2 = *(const ushort4*)(Fz + (long)s1 * 512 + co);
    v.x += bf2f(a.x) + bf2f(b2.x);
    v.y += bf2f(a.y) + bf2f(b2.y);
    v.z += bf2f(a.z) + bf2f(b2.z);
    v.w += bf2f(a.w) + bf2f(b2.w);
  }
  if (j < end) {
    const ushort4 a = *(const ushort4*)(Fz + (long)sp[j] * 512 + co);
    v.x += bf2f(a.x);
    v.y += bf2f(a.y);
    v.z += bf2f(a.z);
    v.w += bf2f(a.w);
  }
  const float inv = 1.f / fmaxf((float)(end - beg), 1.f);
  const ushort4 p4 = *(const ushort4*)(Fz + (long)n * 512 + 256 + co);
  const float o0 = fmaxf(fmaf(v.x, inv, bf2f(p4.x)), 0.f);
  const float o1 = fmaxf(fmaf(v.y, inv, bf2f(p4.y)), 0.f);
  const float o2 = fmaxf(fmaf(v.z, inv, bf2f(p4.z)), 0.f);
  const float o3 = fmaxf(fmaf(v.w, inv, bf2f(p4.w)), 0.f);
  float s = o0 + o1 + o2 + o3;
  float q = o0 * o0 + o1 * o1 + o2 * o2 + o3 * o3;
#pragma unroll
  for (int m = 1; m < 64; m <<= 1) {
    s += __shfl_xor(s, m, 64);
    q += __shfl_xor(q, m, 64);
  }
  const float mean = s * (1.f / H_);
  const float var = q * (1.f / H_) - mean * mean;
  const float r = rsqrtf(var + 1e-5f);
  const float4 gg = *(const float4*)(g + co);
  const float4 bv = *(const float4*)(bb + co);
  float o[4];
  o[0] = (o0 - mean) * r * gg.x + bv.x;
  o[1] = (o1 - mean) * r * gg.y + bv.y;
  o[2] = (o2 - mean) * r * gg.z + bv.z;
  o[3] = (o3 - mean) * r * gg.w + bv.w;
  const long row = ((long)z * N_ + n) * 288 + co;
  ushort4 hv, lv;
  hv.x = f2bf(o[0]); lv.x = f2bf(o[0] - bf2f(hv.x));
  hv.y = f2bf(o[1]); lv.y = f2bf(o[1] - bf2f(hv.y));
  hv.z = f2bf(o[2]); lv.z = f2bf(o[2] - bf2f(hv.z));
  hv.w = f2bf(o[3]); lv.w = f2bf(o[3] - bf2f(hv.w));
  *(ushort4*)(outh + row) = hv;
  *(ushort4*)(outl + row) = lv;
}

// ---------------- pooling (h planes ld 288) ----------------
__launch_bounds__(256) __global__
void pool_k(const u16* __restrict__ hh, const u16* __restrict__ hl,
            const float* __restrict__ sbuf, const int* __restrict__ gb,
            float* __restrict__ pooled, int t0) {
  const int z = blockIdx.y;
  const int g = blockIdx.x;
  const int c = threadIdx.x;
  const int beg = gb[z * (B_ + 1) + g];
  const int end = gb[z * (B_ + 1) + g + 1];
  const float* sz = sbuf + (long)z * N_;
  __shared__ float red[256];
  float m = -1e30f;
  for (int i = beg + c; i < end; i += 256) m = fmaxf(m, sz[i]);
  red[c] = m;
  __syncthreads();
  for (int s = 128; s > 0; s >>= 1) {
    if (c < s) red[c] = fmaxf(red[c], red[c + s]);
    __syncthreads();
  }
  m = red[0];
  __syncthreads();
  float sum = 0.f;
  for (int i = beg + c; i < end; i += 256) sum += expf(sz[i] - m);
  red[c] = sum;
  __syncthreads();
  for (int s = 128; s > 0; s >>= 1) {
    if (c < s) red[c] += red[c + s];
    __syncthreads();
  }
  sum = red[0];
  float acc = 0.f;
  for (int i = beg; i < end; ++i) {
    const float w = expf(sz[i] - m);
    const long idx = ((long)z * N_ + i) * 288 + c;
    acc = fmaf(bf2f(hh[idx]) + bf2f(hl[idx]), w, acc);
  }
  pooled[((long)(t0 + z) * B_ + g) * H_ + c] = (sum > 0.f) ? acc / sum : 0.f;
}

// ---------------- transformer ----------------
__global__ void build_seq_k(const float* __restrict__ pooled, const float* __restrict__ cls,
                            const float* __restrict__ pos, float* __restrict__ seq,
                            u16* __restrict__ sh, u16* __restrict__ sl) {
  const int s = blockIdx.x, b = blockIdx.y, c = threadIdx.x;
  const float v0 = (s == 0) ? cls[c] : pooled[(((long)(s - 1)) * B_ + b) * H_ + c];
  const float v = v0 + pos[(long)s * H_ + c];
  const long o = ((long)b * S_ + s) * H_ + c;
  seq[o] = v;
  const u16 hi = f2bf(v);
  sh[o] = hi;
  sl[o] = f2bf(v - bf2f(hi));
}

__launch_bounds__(256) __global__
void attn_k(const float* __restrict__ qkv, u16* __restrict__ oh, u16* __restrict__ ol) {
  const int b = blockIdx.x, h = blockIdx.y;
  __shared__ float qs[S_][DH_], ks[S_][DH_], vs[S_][DH_], att[S_][S_];
  const int tid = threadIdx.x;
  for (int i = tid; i < S_ * DH_; i += 256) {
    const int s = i / DH_, d = i % DH_;
    const long base = ((long)b * S_ + s) * (3 * H_) + h * DH_ + d;
    qs[s][d] = qkv[base];
    ks[s][d] = qkv[base + H_];
    vs[s][d] = qkv[base + 2 * H_];
  }
  __syncthreads();
  for (int i = tid; i < S_ * S_; i += 256) {
    const int r = i / S_, c2 = i % S_;
    float acc = 0.f;
#pragma unroll
    for (int d = 0; d < DH_; ++d) acc = fmaf(qs[r][d], ks[c2][d], acc);
    att[r][c2] = acc * 0.17677669529663687f;
  }
  __syncthreads();
  if (tid < S_) {
    float m = -1e30f;
    for (int j = 0; j < S_; ++j) m = fmaxf(m, att[tid][j]);
    float sum = 0.f;
    for (int j = 0; j < S_; ++j) {
      const float e = expf(att[tid][j] - m);
      att[tid][j] = e;
      sum += e;
    }
    const float inv = 1.f / sum;
    for (int j = 0; j < S_; ++j) att[tid][j] *= inv;
  }
  __syncthreads();
  for (int i = tid; i < S_ * DH_; i += 256) {
    const int s = i / DH_, d = i % DH_;
    float acc = 0.f;
#pragma unroll
    for (int j = 0; j < S_; ++j) acc = fmaf(att[s][j], vs[j][d], acc);
    const long o = ((long)b * S_ + s) * H_ + h * DH_ + d;
    const u16 hi = f2bf(acc);
    oh[o] = hi;
    ol[o] = f2bf(acc - bf2f(hi));
  }
}

__launch_bounds__(256) __global__
void resid_ln_k(float* __restrict__ seq, const float* __restrict__ add,
                const float* __restrict__ g, const float* __restrict__ bb,
                u16* __restrict__ sh, u16* __restrict__ sl) {
  const int row = blockIdx.x, c = threadIdx.x;
  const float v = seq[(long)row * H_ + c] + add[(long)row * H_ + c];
  __shared__ float rs[256], rq[256];
  rs[c] = v;
  rq[c] = v * v;
  __syncthreads();
  for (int s = 128; s > 0; s >>= 1) {
    if (c < s) {
      rs[c] += rs[c + s];
      rq[c] += rq[c + s];
    }
    __syncthreads();
  }
  const float mean = rs[0] * (1.f / H_);
  const float var = rq[0] * (1.f / H_) - mean * mean;
  const float o = (v - mean) * rsqrtf(var + 1e-5f) * g[c] + bb[c];
  const long idx = (long)row * H_ + c;
  seq[idx] = o;
  const u16 hi = f2bf(o);
  sh[idx] = hi;
  sl[idx] = f2bf(o - bf2f(hi));
}

__launch_bounds__(256) __global__
void head_k(const float* __restrict__ seq, const float* __restrict__ hw,
            const float* __restrict__ hb, float* __restrict__ out) {
  const int b = blockIdx.x, c = threadIdx.x;
  const float x = seq[(long)b * S_ * H_ + c];
  __shared__ float rs[256];
  for (int o = 0; o < OUT_; ++o) {
    rs[c] = x * hw[c * OUT_ + o];
    __syncthreads();
    for (int s = 128; s > 0; s >>= 1) {
      if (c < s) rs[c] += rs[c + s];
      __syncthreads();
    }
    if (c == 0) {
      const float v = rs[0] + hb[o];
      out[b * OUT_ + o] = fmaxf(v, 0.f) + log1pf(expf(-fabsf(v)));
    }
    __syncthreads();
  }
}

// ---------------- launcher ----------------
extern "C" void kernel_launch(void* const* d_in, const int* in_sizes, int n_in,
                              void* d_out, int out_size, void* d_ws, size_t ws_size,
                              hipStream_t stream) {
  const float* x = (const float*)d_in[0];
  const float* ea = (const float*)d_in[1];
  const int* ei = (const int*)d_in[2];
  const int* batch = (const int*)d_in[3];
  const float* nw0 = (const float*)d_in[4];
  const float* nb0 = (const float*)d_in[5];
  const float* rw0 = (const float*)d_in[6];
  const float* rb0 = (const float*)d_in[7];
  const float* lg0 = (const float*)d_in[8];
  const float* lb0 = (const float*)d_in[9];
  const float* nw1 = (const float*)d_in[10];
  const float* nb1 = (const float*)d_in[11];
  const float* rw1 = (const float*)d_in[12];
  const float* rb1 = (const float*)d_in[13];
  const float* lg1 = (const float*)d_in[14];
  const float* lb1 = (const float*)d_in[15];
  const float* ppw = (const float*)d_in[16];
  const float* ppb = (const float*)d_in[17];
  const float* psw = (const float*)d_in[18];
  // d_in[19] = psb: dropped (softmax shift-invariant)
  const float* pos = (const float*)d_in[20];
  const float* cls = (const float*)d_in[21];
  const float* qkvw = (const float*)d_in[22];
  const float* qkvbias = (const float*)d_in[23];
  const float* outw = (const float*)d_in[24];
  const float* outb = (const float*)d_in[25];
  const float* f1w = (const float*)d_in[26];
  const float* f1b = (const float*)d_in[27];
  const float* f2w = (const float*)d_in[28];
  const float* f2b = (const float*)d_in[29];
  const float* l1g = (const float*)d_in[30];
  const float* l1b = (const float*)d_in[31];
  const float* l2g = (const float*)d_in[32];
  const float* l2b = (const float*)d_in[33];
  const float* hw = (const float*)d_in[34];
  const float* hb = (const float*)d_in[35];
  float* out = (float*)d_out;

  // ---- workspace carve ----
  char* cur = (char*)d_ws;
  auto alloc = [&](long bytes) {
    char* p = cur;
    cur += (bytes + 255) & ~255L;
    return (void*)p;
  };
  float* pooled = (float*)alloc((long)T_ * B_ * H_ * 4);
  float* seq = (float*)alloc((long)M_TX * H_ * 4);
  u16* seqh = (u16*)alloc((long)M_TX * H_ * 2);
  u16* seql = (u16*)alloc((long)M_TX * H_ * 2);
  float* qkvbuf = (float*)alloc((long)M_TX * 3 * H_ * 4);
  float* obuf_f = (float*)alloc((long)M_TX * H_ * 4);
  u16* obufh = (u16*)alloc((long)M_TX * H_ * 2);
  u16* obufl = (u16*)alloc((long)M_TX * H_ * 2);
  u16* ffh = (u16*)alloc((long)M_TX * DFF_ * 2);
  u16* ffl = (u16*)alloc((long)M_TX * DFF_ * 2);
  u16* w0h = (u16*)alloc(512L * 160 * 2);
  u16* w0l = (u16*)alloc(512L * 160 * 2);
  u16* w1h = (u16*)alloc(512L * 288 * 2);
  u16* w1l = (u16*)alloc(512L * 288 * 2);
  u16* ppwh = (u16*)alloc(256L * 256 * 2);
  u16* ppwl = (u16*)alloc(256L * 256 * 2);
  u16* qkvwh = (u16*)alloc((long)L_ * 768 * 256 * 2);
  u16* qkvwl = (u16*)alloc((long)L_ * 768 * 256 * 2);
  u16* outwh = (u16*)alloc((long)L_ * 256 * 256 * 2);
  u16* outwl = (u16*)alloc((long)L_ * 256 * 256 * 2);
  u16* f1wh = (u16*)alloc((long)L_ * 2048 * 256 * 2);
  u16* f1wl = (u16*)alloc((long)L_ * 2048 * 256 * 2);
  u16* f2wh = (u16*)alloc((long)L_ * 256 * 2048 * 2);
  u16* f2wl = (u16*)alloc((long)L_ * 256 * 2048 * 2);
  float* bias0c = (float*)alloc(512 * 4);
  float* bias1c = (float*)alloc(512 * 4);
  const long fixed_used = cur - (char*)d_ws;

  const long perday = (long)N_ * 160 * 2 * 2      // xh/xl (K-ext)
                      + (long)N_ * 512 * 2        // bufF (bf16)
                      + (long)N_ * 288 * 2 * 2    // bufD planes (K-ext)
                      + (long)N_ * 4              // sbuf
                      + (2L * E_ + 3L * N_ + (N_ + 1) + (B_ + 1)) * 4 + 8192;
  int DT = 16;
  while (DT > 1 && (size_t)(fixed_used + (long)DT * perday) > ws_size) DT >>= 1;

  u16* xh = (u16*)alloc((long)DT * N_ * 160 * 2);
  u16* xl = (u16*)alloc((long)DT * N_ * 160 * 2);
  u16* bufF = (u16*)alloc((long)DT * N_ * 512 * 2);
  u16* bufDh = (u16*)alloc((long)DT * N_ * 288 * 2);
  u16* bufDl = (u16*)alloc((long)DT * N_ * 288 * 2);
  float* sbuf = (float*)alloc((long)DT * N_ * 4);
  int* elist = (int*)alloc((long)DT * E_ * 4);
  int* srcs = (int*)alloc((long)DT * E_ * 4);
  int* offs = (int*)alloc((long)DT * (N_ + 1) * 4);
  int* cursor = (int*)alloc((long)DT * N_ * 4);
  int* deg = (int*)alloc((long)DT * N_ * 4);
  int* gb = (int*)alloc((long)DT * (B_ + 1) * 4);

  auto zero = [&](float* p, long n) {
    zero_k<<<dim3((unsigned)((n + 255) / 256)), 256, 0, stream>>>(p, n);
  };

  // ---- weight prep (once per launch) ----
  wzero_k<<<dim3((unsigned)((512L * 160 + 255) / 256)), 256, 0, stream>>>(w0h, 512L * 160);
  wzero_k<<<dim3((unsigned)((512L * 160 + 255) / 256)), 256, 0, stream>>>(w0l, 512L * 160);
  wzero_k<<<dim3((unsigned)((512L * 288 + 255) / 256)), 256, 0, stream>>>(w1h, 512L * 288);
  wzero_k<<<dim3((unsigned)((512L * 288 + 255) / 256)), 256, 0, stream>>>(w1l, 512L * 288);
  wtrans_k<<<dim3(16, 8), 256, 0, stream>>>(nw0, 256, w0h, w0l, 0, 0, 160);
  wtrans_k<<<dim3(16, 8), 256, 0, stream>>>(rw0, 256, w0h, w0l, 256, 0, 160);
  wtrans_k<<<dim3(16, 1), 256, 0, stream>>>(nw0 + 128L * 256, 256, w0h, w0l, 256, 128, 160);
  wtrans_k<<<dim3(16, 16), 256, 0, stream>>>(nw1, 256, w1h, w1l, 0, 0, 288);
  wtrans_k<<<dim3(16, 16), 256, 0, stream>>>(rw1, 256, w1h, w1l, 256, 0, 288);
  wtrans_k<<<dim3(16, 1), 256, 0, stream>>>(nw1 + 256L * 256, 256, w1h, w1l, 256, 256, 288);
  wtrans_k<<<dim3(16, 16), 256, 0, stream>>>(ppw, 256, ppwh, ppwl, 0, 0, 256);
  for (int l = 0; l < L_; ++l) {
    wtrans_k<<<dim3(48, 16), 256, 0, stream>>>(qkvw + (long)l * 256 * 768, 768,
                                               qkvwh + (long)l * 768 * 256,
                                               qkvwl + (long)l * 768 * 256, 0, 0, 256);
    wtrans_k<<<dim3(16, 16), 256, 0, stream>>>(outw + (long)l * 256 * 256, 256,
                                               outwh + (long)l * 256 * 256,
                                               outwl + (long)l * 256 * 256, 0, 0, 256);
    wtrans_k<<<dim3(128, 16), 256, 0, stream>>>(f1w + (long)l * 256 * 2048, 2048,
                                                f1wh + (long)l * 2048 * 256,
                                                f1wl + (long)l * 2048 * 256, 0, 0, 256);
    wtrans_k<<<dim3(16, 128), 256, 0, stream>>>(f2w + (long)l * 2048 * 256, 256,
                                                f2wh + (long)l * 256 * 2048,
                                                f2wl + (long)l * 256 * 2048, 0, 0, 2048);
  }
  biascat_k<<<1, 512, 0, stream>>>(nb0, rb0, bias0c);
  biascat_k<<<1, 512, 0, stream>>>(nb1, rb1, bias1c);

  for (int t0 = 0; t0 < T_; t0 += DT) {
    const int zc = DT;
    // ----- CSR + bounds + x split + eagg K-ext fill -----
    zero((float*)deg, (long)zc * N_);
    deg_k<<<dim3(E_ / 256, zc), 256, 0, stream>>>(ei, deg, t0);
    scan_k<<<dim3(zc), 256, 0, stream>>>(deg, offs, cursor);
    fill_k<<<dim3(E_ / 256, zc), 256, 0, stream>>>(ei, cursor, elist, srcs, t0);
    bounds_k<<<dim3(zc), 128, 0, stream>>>(batch, gb, t0);
    {
      const long nx = (long)zc * N_ * 128;
      splitx_k<<<dim3((unsigned)(nx / 256)), 256, 0, stream>>>(x + (long)t0 * N_ * IN_,
                                                               xh, xl, nx);
    }
    eagg_k<<<dim3(N_ / 8, zc), 256, 0, stream>>>(ea, elist, offs, xh, xl, bufDh, bufDl, t0);
    // ----- conv layer 0: fused [neigh|root+eagg] GEMM -> bf16 bufF -----
    gemm_bf<0, 1, 2><<<dim3(4, zc * (N_ / 64)), 256, 0, stream>>>(
        xh, xl, 160, w0h, w0l, 160, bias0c, nullptr, bufF, nullptr, 512, 160,
        nullptr, nullptr);
    conv_gather_k<<<dim3(N_ / 4, zc), 256, 0, stream>>>(bufF, srcs, offs, lg0, lb0,
                                                        bufDh, bufDl);
    // ----- conv layer 1 -----
    gemm_bf<0, 1, 2><<<dim3(4, zc * (N_ / 64)), 256, 0, stream>>>(
        bufDh, bufDl, 288, w1h, w1l, 288, bias1c, nullptr, bufF, nullptr, 512, 288,
        nullptr, nullptr);
    conv_gather_k<<<dim3(N_ / 4, zc), 256, 0, stream>>>(bufF, srcs, offs, lg1, lb1,
                                                        bufDh, bufDl);
    // ----- pooling: fused proj+tanh+score epilogue, then segment softmax -----
    zero(sbuf, (long)zc * N_);
    gemm_bf<3, 1, 0><<<dim3(2, zc * (N_ / 64)), 256, 0, stream>>>(
        bufDh, bufDl, 288, ppwh, ppwl, 256, ppb, nullptr, nullptr, nullptr, 0, 256,
        sbuf, psw);
    pool_k<<<dim3(B_, zc), 256, 0, stream>>>(bufDh, bufDl, sbuf, gb, pooled, t0);
  }

  // ----- temporal transformer -----
  build_seq_k<<<dim3(S_, B_), 256, 0, stream>>>(pooled, cls, pos, seq, seqh, seql);
  for (int l = 0; l < L_; ++l) {
    gemm_bf<0, 1, 0><<<dim3(6, M_TX / 64), 256, 0, stream>>>(
        seqh, seql, 256, qkvwh + (long)l * 768 * 256, qkvwl + (long)l * 768 * 256, 256,
        qkvbias + (long)l * 768, qkvbuf, nullptr, nullptr, 768, 256, nullptr, nullptr);
    attn_k<<<dim3(B_, HEADS_), 256, 0, stream>>>(qkvbuf, obufh, obufl);
    gemm_bf<0, 1, 0><<<dim3(2, M_TX / 64), 256, 0, stream>>>(
        obufh, obufl, 256, outwh + (long)l * 256 * 256, outwl + (long)l * 256 * 256, 256,
        outb + (long)l * H_, obuf_f, nullptr, nullptr, 256, 256, nullptr, nullptr);
    resid_ln_k<<<dim3(M_TX), 256, 0, stream>>>(seq, obuf_f, l1g + (long)l * H_,
                                               l1b + (long)l * H_, seqh, seql);
    gemm_bf<1, 1, 1><<<dim3(16, M_TX / 64), 256, 0, stream>>>(
        seqh, seql, 256, f1wh + (long)l * 2048 * 256, f1wl + (long)l * 2048 * 256, 256,
        f1b + (long)l * DFF_, nullptr, ffh, ffl, 2048, 256, nullptr, nullptr);
    zero(obuf_f, (long)M_TX * H_);
    gemm_bf<0, 8, 0><<<dim3(2, M_TX / 64, 8), 256, 0, stream>>>(
        ffh, ffl, 2048, f2wh + (long)l * 256 * 2048, f2wl + (long)l * 256 * 2048, 2048,
        f2b + (long)l * H_, obuf_f, nullptr, nullptr, 256, 2048, nullptr, nullptr);
    resid_ln_k<<<dim3(M_TX), 256, 0, stream>>>(seq, obuf_f, l2g + (long)l * H_,
                                               l2b + (long)l * H_, seqh, seql);
  }
  head_k<<<dim3(B_), 256, 0, stream>>>(seq, hw, hb, out);
}